// Round 1
// baseline (372.785 us; speedup 1.0000x reference)
//
#include <hip/hip_runtime.h>

// Reverb via FFT overlap-save cross-correlation.
// L = 2^20 = 4^10 complex FFT, radix-4 Stockham autosort (10 stages, all
// global-memory passes, perfectly coalesced reads at g + q*L/4).
// 4 overlap-save segments, real-packed 2-per-complex-FFT; IR rides as batch
// slot 2 of the forward pass. Inverse FFT via conj trick reuses the same
// forward stage kernel. Epilogue: slice valid region, fused max-abs
// reduction (atomicMax on fabs bits), then normalize.

#define L_FFT (1 << 20)   // 1,048,576 = 4^10

__device__ __forceinline__ float2 cmul(float2 a, float2 b) {
    return make_float2(a.x * b.x - a.y * b.y, a.x * b.y + a.y * b.x);
}

// Build batch-3 complex input: slot0 = seg0 + i*seg1, slot1 = seg2 + i*seg3,
// slot2 = ir (zero-padded, imag 0). Audio treated as 0 beyond N (covers the
// reference's trailing M-1 zero pad).
__global__ void pack_kernel(const float* __restrict__ audio,
                            const float* __restrict__ ir,
                            float2* __restrict__ A, int N, int M, int V) {
    const int L = L_FFT;
    int i = blockIdx.x * blockDim.x + threadIdx.x;   // [0, L)
    int i1 = i + V, i2 = i + 2 * V, i3 = i + 3 * V;
    float x0 = (i  < N) ? audio[i]  : 0.f;
    float x1 = (i1 < N) ? audio[i1] : 0.f;
    float x2 = (i2 < N) ? audio[i2] : 0.f;
    float x3 = (i3 < N) ? audio[i3] : 0.f;
    A[i]         = make_float2(x0, x1);
    A[L + i]     = make_float2(x2, x3);
    A[2 * L + i] = make_float2((i < M) ? ir[i] : 0.f, 0.f);
}

// One radix-4 Stockham DIF stage. s = log2(J), J = 4^t. batch via blockIdx.y.
// Reads src[g + q*L/4]; writes dst[4*(g-j)+j + r*J] with twiddle w^(n'*r),
// w = exp(-2*pi*i/Ln), Ln = L >> s.
__global__ void fft_stage(const float2* __restrict__ src,
                          float2* __restrict__ dst, int s) {
    const int L = L_FFT;
    int g = blockIdx.x * blockDim.x + threadIdx.x;   // [0, L/4)
    size_t boff = (size_t)blockIdx.y * L;
    const float2* sb = src + boff;
    float2* db = dst + boff;
    int J = 1 << s;
    int j = g & (J - 1);
    int np = g >> s;

    float2 a = sb[g];
    float2 b = sb[g + (L >> 2)];
    float2 c = sb[g + (L >> 1)];
    float2 d = sb[g + 3 * (L >> 2)];

    float2 apc = make_float2(a.x + c.x, a.y + c.y);
    float2 amc = make_float2(a.x - c.x, a.y - c.y);
    float2 bpd = make_float2(b.x + d.x, b.y + d.y);
    float2 bmd = make_float2(b.x - d.x, b.y - d.y);

    float2 S0 = make_float2(apc.x + bpd.x, apc.y + bpd.y);
    float2 S2 = make_float2(apc.x - bpd.x, apc.y - bpd.y);
    float2 S1 = make_float2(amc.x + bmd.y, amc.y - bmd.x);  // amc + (-i)*bmd
    float2 S3 = make_float2(amc.x - bmd.y, amc.y + bmd.x);  // amc + ( i)*bmd

    int Ln = L >> s;
    float ang = -6.28318530717958647692f * ((float)np / (float)Ln);
    float s1, c1;
    __sincosf(ang, &s1, &c1);
    float c2 = c1 * c1 - s1 * s1, s2 = 2.f * c1 * s1;
    float c3 = c1 * c2 - s1 * s2, s3 = s1 * c2 + c1 * s2;

    int ob = ((g - j) << 2) + j;
    db[ob]         = S0;
    db[ob + J]     = cmul(S1, make_float2(c1, s1));
    db[ob + 2 * J] = cmul(S2, make_float2(c2, s2));
    db[ob + 3 * J] = cmul(S3, make_float2(c3, s3));
}

// Un-pack the two real spectra per packed FFT, multiply by conj(H)
// (circular cross-correlation), repack P = G0 + i*G1, and store conj(P)
// so the inverse transform can reuse the forward stage kernel.
__global__ void spectral_kernel(const float2* __restrict__ A,
                                float2* __restrict__ B) {
    const int L = L_FFT;
    int k = blockIdx.x * blockDim.x + threadIdx.x;   // [0, L)
    int kr = (L - k) & (L - 1);
    float2 H = A[2 * L + k];
    float hx = H.x, hy = H.y;
#pragma unroll
    for (int p = 0; p < 2; ++p) {
        float2 Z  = A[p * L + k];
        float2 Zr = A[p * L + kr];
        // X0 = (Z + conj(Zr))/2 ; X1 = -i*(Z - conj(Zr))/2
        float2 X0 = make_float2(0.5f * (Z.x + Zr.x), 0.5f * (Z.y - Zr.y));
        float2 X1 = make_float2(0.5f * (Z.y + Zr.y), 0.5f * (Zr.x - Z.x));
        // G = X * conj(H)
        float2 G0 = make_float2(X0.x * hx + X0.y * hy, X0.y * hx - X0.x * hy);
        float2 G1 = make_float2(X1.x * hx + X1.y * hy, X1.y * hx - X1.x * hy);
        // P = G0 + i*G1, write conj(P)
        float2 P = make_float2(G0.x - G1.y, G0.y + G1.x);
        B[p * L + k] = make_float2(P.x, -P.y);
    }
}

// q = FFT(conj(P)); time-domain packed result w = conj(q)/L = corr_even + i*corr_odd.
// Slice the valid overlap-save region to d_out and fold in max-abs reduction.
__global__ void slice_max_kernel(const float2* __restrict__ R,
                                 float* __restrict__ out,
                                 unsigned* __restrict__ maxcell,
                                 int N, int V) {
    const int L = L_FFT;
    const float invL = 1.0f / (float)L_FFT;
    int t = blockIdx.x * blockDim.x + threadIdx.x;
    float v = 0.f;
    if (t < N) {
        int sidx = t / V;              // 0..3
        int n = t - sidx * V;          // n < V <= L - M
        float2 q = R[(size_t)(sidx >> 1) * L + n];
        v = (sidx & 1) ? (-q.y * invL) : (q.x * invL);
        out[t] = v;
    }
    // block max of |v|
    float m = fabsf(v);
    for (int o = 32; o > 0; o >>= 1) m = fmaxf(m, __shfl_xor(m, o));
    __shared__ float sm[4];
    int lane = threadIdx.x & 63, wave = threadIdx.x >> 6;
    if (lane == 0) sm[wave] = m;
    __syncthreads();
    if (threadIdx.x == 0) {
        m = fmaxf(fmaxf(sm[0], sm[1]), fmaxf(sm[2], sm[3]));
        atomicMax(maxcell, __float_as_uint(m));  // fabs bits: uint order == float order
    }
}

__global__ void normalize_kernel(float* __restrict__ out,
                                 const unsigned* __restrict__ maxcell, int N) {
    int t = blockIdx.x * blockDim.x + threadIdx.x;
    if (t >= N) return;
    float mx = __uint_as_float(*maxcell);
    out[t] = out[t] / mx;
}

extern "C" void kernel_launch(void* const* d_in, const int* in_sizes, int n_in,
                              void* d_out, int out_size, void* d_ws, size_t ws_size,
                              hipStream_t stream) {
    const int L = L_FFT;
    const float* audio = (const float*)d_in[0];
    const float* ir    = (const float*)d_in[1];
    float* out = (float*)d_out;

    const int N = in_sizes[0];          // 2,646,000
    const int M = in_sizes[1];          // 220,500
    const int V = L - M + 1;            // 828,077 valid outputs per segment

    float2* A = (float2*)d_ws;
    float2* B = A + (size_t)3 * L;
    unsigned* cell = (unsigned*)(B + (size_t)3 * L);

    hipMemsetAsync(cell, 0, sizeof(unsigned), stream);

    // stage buffers: pack -> A
    pack_kernel<<<L / 256, 256, 0, stream>>>(audio, ir, A, N, M, V);

    // forward FFT, batch 3 (seg01, seg23, ir). 10 stages: A->B->A...->A
    for (int t = 0; t < 10; ++t) {
        const float2* src = (t & 1) ? B : A;
        float2* dst       = (t & 1) ? A : B;
        fft_stage<<<dim3(L / 4 / 256, 3), 256, 0, stream>>>(src, dst, 2 * t);
    }
    // spectra in A; correlation multiply + conj-repack -> B
    spectral_kernel<<<L / 256, 256, 0, stream>>>(A, B);

    // inverse (as forward of conj), batch 2. 10 stages: B->A->B...->B
    for (int t = 0; t < 10; ++t) {
        const float2* src = (t & 1) ? A : B;
        float2* dst       = (t & 1) ? B : A;
        fft_stage<<<dim3(L / 4 / 256, 2), 256, 0, stream>>>(src, dst, 2 * t);
    }
    // result in B
    int nblk = (N + 255) / 256;
    slice_max_kernel<<<nblk, 256, 0, stream>>>(B, out, cell, N, V);
    normalize_kernel<<<nblk, 256, 0, stream>>>(out, cell, N);
}

// Round 2
// 203.545 us; speedup vs baseline: 1.8315x; 1.8315x over previous
//
#include <hip/hip_runtime.h>

// Reverb via FFT overlap-save cross-correlation.
// L = 2^20 = 16^5 complex FFT, radix-16 Stockham autosort (5 global stages,
// 16-pt DFT in registers as nested 4x4 radix-4). 4 overlap-save segments,
// real-packed 2-per-complex-FFT; IR rides as batch slot 2 of the forward
// pass. Inverse FFT via conj trick reuses the same forward stage kernel.
// Epilogue: max via partials array (no same-address atomics — R1 showed a
// 120us atomicMax hotspot), tree reduce, then slice+normalize in one pass.

#define L_FFT (1 << 20)   // 1,048,576 = 16^5

__device__ __forceinline__ float2 cmul(float2 a, float2 b) {
    return make_float2(a.x * b.x - a.y * b.y, a.x * b.y + a.y * b.x);
}

// radix-4 DFT: o_r = a + b*w4^r + c*w4^{2r} + d*w4^{3r}, w4 = -i
__device__ __forceinline__ void rad4(float2 a, float2 b, float2 c, float2 d,
                                     float2& o0, float2& o1, float2& o2, float2& o3) {
    float2 apc = make_float2(a.x + c.x, a.y + c.y);
    float2 amc = make_float2(a.x - c.x, a.y - c.y);
    float2 bpd = make_float2(b.x + d.x, b.y + d.y);
    float2 bmd = make_float2(b.x - d.x, b.y - d.y);
    o0 = make_float2(apc.x + bpd.x, apc.y + bpd.y);
    o2 = make_float2(apc.x - bpd.x, apc.y - bpd.y);
    o1 = make_float2(amc.x + bmd.y, amc.y - bmd.x);  // amc + (-i)*bmd
    o3 = make_float2(amc.x - bmd.y, amc.y + bmd.x);  // amc + ( i)*bmd
}

// Build batch-3 complex input: slot0 = seg0 + i*seg1, slot1 = seg2 + i*seg3,
// slot2 = ir (zero-padded, imag 0).
__global__ void pack_kernel(const float* __restrict__ audio,
                            const float* __restrict__ ir,
                            float2* __restrict__ A, int N, int M, int V) {
    const int L = L_FFT;
    int i = blockIdx.x * blockDim.x + threadIdx.x;   // [0, L)
    int i1 = i + V, i2 = i + 2 * V, i3 = i + 3 * V;
    float x0 = (i  < N) ? audio[i]  : 0.f;
    float x1 = (i1 < N) ? audio[i1] : 0.f;
    float x2 = (i2 < N) ? audio[i2] : 0.f;
    float x3 = (i3 < N) ? audio[i3] : 0.f;
    A[i]         = make_float2(x0, x1);
    A[L + i]     = make_float2(x2, x3);
    A[2 * L + i] = make_float2((i < M) ? ir[i] : 0.f, 0.f);
}

// One radix-16 Stockham DIF stage. t4 = 4*t, J = 16^t. batch via blockIdx.y.
// Reads src[g + q*L/16] (coalesced); 16-pt DFT in registers; writes
// dst[16*(g-j)+j + r*J] with stage twiddle w_Ln^{np*r}, Ln = L >> t4.
__global__ void fft_stage16(const float2* __restrict__ src,
                            float2* __restrict__ dst, int t4) {
    const int L = L_FFT;
    int g = blockIdx.x * blockDim.x + threadIdx.x;   // [0, L/16)
    size_t boff = (size_t)blockIdx.y * L;
    const float2* sb = src + boff;
    float2* db = dst + boff;
    int J = 1 << t4;
    int j = g & (J - 1);
    int np = g >> t4;
    int Ln = L >> t4;

    float2 x[16];
#pragma unroll
    for (int q = 0; q < 16; ++q) x[q] = sb[g + q * (L >> 4)];

    // step 1: 4 radix-4 DFTs over q2 (x[q1 + 4*q2]) -> tt[q1*4 + r2]
    float2 tt[16];
    rad4(x[0], x[4], x[8],  x[12], tt[0],  tt[1],  tt[2],  tt[3]);
    rad4(x[1], x[5], x[9],  x[13], tt[4],  tt[5],  tt[6],  tt[7]);
    rad4(x[2], x[6], x[10], x[14], tt[8],  tt[9],  tt[10], tt[11]);
    rad4(x[3], x[7], x[11], x[15], tt[12], tt[13], tt[14], tt[15]);

    // step 2: tt[q1*4 + r2] *= w16^{q1*r2}, w16 = exp(-2*pi*i/16)
    const float C1 = 0.92387953251128675613f, S1 = 0.38268343236508977173f;
    const float C2 = 0.70710678118654752440f;
    const float2 W1 = make_float2( C1, -S1);
    const float2 W2 = make_float2( C2, -C2);
    const float2 W3 = make_float2( S1, -C1);
    const float2 W6 = make_float2(-C2, -C2);
    const float2 W9 = make_float2(-C1,  S1);
    tt[5]  = cmul(tt[5],  W1);
    tt[6]  = cmul(tt[6],  W2);
    tt[7]  = cmul(tt[7],  W3);
    tt[9]  = cmul(tt[9],  W2);
    tt[10] = make_float2(tt[10].y, -tt[10].x);   // * w16^4 = -i
    tt[11] = cmul(tt[11], W6);
    tt[13] = cmul(tt[13], W3);
    tt[14] = cmul(tt[14], W6);
    tt[15] = cmul(tt[15], W9);

    // step 3: 4 radix-4 DFTs over q1 -> y[r2 + 4*r1]
    float2 y[16];
    rad4(tt[0], tt[4], tt[8],  tt[12], y[0], y[4], y[8],  y[12]);
    rad4(tt[1], tt[5], tt[9],  tt[13], y[1], y[5], y[9],  y[13]);
    rad4(tt[2], tt[6], tt[10], tt[14], y[2], y[6], y[10], y[14]);
    rad4(tt[3], tt[7], tt[11], tt[15], y[3], y[7], y[11], y[15]);

    // stage twiddle + store. |ang| < 2*pi/16 so sincos is well-conditioned;
    // w^r by chain multiply (<=15 cmuls, ~1e-6 rel err).
    float ang = -6.28318530717958647692f * ((float)np / (float)Ln);
    float sa, ca;
    __sincosf(ang, &sa, &ca);
    float2 w1 = make_float2(ca, sa);
    int ob = ((g - j) << 4) + j;
    db[ob] = y[0];
    float2 w = w1;
#pragma unroll
    for (int r = 1; r < 16; ++r) {
        db[ob + r * J] = cmul(y[r], w);
        w = cmul(w, w1);
    }
}

// Un-pack the two real spectra per packed FFT, multiply by conj(H)
// (cross-correlation), repack P = G0 + i*G1, store conj(P) so the inverse
// transform reuses the forward stage kernel.
__global__ void spectral_kernel(const float2* __restrict__ S,
                                float2* __restrict__ D) {
    const int L = L_FFT;
    int k = blockIdx.x * blockDim.x + threadIdx.x;   // [0, L)
    int kr = (L - k) & (L - 1);
    float2 H = S[2 * L + k];
    float hx = H.x, hy = H.y;
#pragma unroll
    for (int p = 0; p < 2; ++p) {
        float2 Z  = S[p * L + k];
        float2 Zr = S[p * L + kr];
        float2 X0 = make_float2(0.5f * (Z.x + Zr.x), 0.5f * (Z.y - Zr.y));
        float2 X1 = make_float2(0.5f * (Z.y + Zr.y), 0.5f * (Zr.x - Z.x));
        float2 G0 = make_float2(X0.x * hx + X0.y * hy, X0.y * hx - X0.x * hy);
        float2 G1 = make_float2(X1.x * hx + X1.y * hy, X1.y * hx - X1.x * hy);
        float2 P = make_float2(G0.x - G1.y, G0.y + G1.x);
        D[p * L + k] = make_float2(P.x, -P.y);
    }
}

// Per-block max of |valid samples| -> partials (no atomics). 2D grid:
// blockIdx.y = segment, x grid-strides over the segment.
__global__ void max_kernel(const float2* __restrict__ R,
                           float* __restrict__ partials, int N, int V) {
    int sidx = blockIdx.y;
    int segLen = (sidx < 3) ? V : (N - 3 * V);
    const float2* Rb = R + (size_t)(sidx >> 1) * L_FFT;
    int stride = gridDim.x * blockDim.x;
    float m = 0.f;
    for (int n = blockIdx.x * blockDim.x + threadIdx.x; n < segLen; n += stride) {
        float2 q = Rb[n];
        float v = (sidx & 1) ? q.y : q.x;    // sign irrelevant under fabs
        m = fmaxf(m, fabsf(v));
    }
    for (int o = 32; o > 0; o >>= 1) m = fmaxf(m, __shfl_xor(m, o));
    __shared__ float sm[4];
    int lane = threadIdx.x & 63, wave = threadIdx.x >> 6;
    if (lane == 0) sm[wave] = m;
    __syncthreads();
    if (threadIdx.x == 0)
        partials[blockIdx.y * gridDim.x + blockIdx.x] =
            fmaxf(fmaxf(sm[0], sm[1]), fmaxf(sm[2], sm[3]));
}

__global__ void reduce_kernel(const float* __restrict__ partials,
                              float* __restrict__ cell, int np) {
    float m = 0.f;
    for (int i = threadIdx.x; i < np; i += blockDim.x) m = fmaxf(m, partials[i]);
    for (int o = 32; o > 0; o >>= 1) m = fmaxf(m, __shfl_xor(m, o));
    __shared__ float sm[4];
    int lane = threadIdx.x & 63, wave = threadIdx.x >> 6;
    if (lane == 0) sm[wave] = m;
    __syncthreads();
    if (threadIdx.x == 0)
        cell[0] = fmaxf(fmaxf(sm[0], sm[1]), fmaxf(sm[2], sm[3]));
}

// Slice valid region and normalize in one pass. The 1/L FFT scale cancels
// in v/max, so raw FFT outputs are used for both.
__global__ void slice_norm_kernel(const float2* __restrict__ R,
                                  float* __restrict__ out,
                                  const float* __restrict__ cell,
                                  int N, int V) {
    int sidx = blockIdx.y;
    int segLen = (sidx < 3) ? V : (N - 3 * V);
    int n = blockIdx.x * blockDim.x + threadIdx.x;
    if (n >= segLen) return;
    float mx = *cell;
    float2 q = R[(size_t)(sidx >> 1) * L_FFT + n];
    float v = (sidx & 1) ? -q.y : q.x;       // w = conj(q)/L
    out[sidx * V + n] = v / mx;
}

extern "C" void kernel_launch(void* const* d_in, const int* in_sizes, int n_in,
                              void* d_out, int out_size, void* d_ws, size_t ws_size,
                              hipStream_t stream) {
    const int L = L_FFT;
    const float* audio = (const float*)d_in[0];
    const float* ir    = (const float*)d_in[1];
    float* out = (float*)d_out;

    const int N = in_sizes[0];          // 2,646,000
    const int M = in_sizes[1];          // 220,500
    const int V = L - M + 1;            // 828,077 valid outputs per segment

    float2* A = (float2*)d_ws;
    float2* B = A + (size_t)3 * L;
    // A[2L..3L) is dead after the forward FFT (inverse uses slots 0,1 only)
    float* partials = (float*)(A + (size_t)2 * L);
    float* cell = partials + 1024;

    pack_kernel<<<L / 256, 256, 0, stream>>>(audio, ir, A, N, M, V);

    // forward FFT, batch 3 (seg01, seg23, ir): A->B->A->B->A->B
    for (int t = 0; t < 5; ++t) {
        const float2* src = (t & 1) ? B : A;
        float2* dst       = (t & 1) ? A : B;
        fft_stage16<<<dim3(L / 16 / 256, 3), 256, 0, stream>>>(src, dst, 4 * t);
    }
    // spectra in B; correlation multiply + conj-repack -> A (slots 0,1)
    spectral_kernel<<<L / 256, 256, 0, stream>>>(B, A);

    // inverse (as forward of conj), batch 2: A->B->...->B
    for (int t = 0; t < 5; ++t) {
        const float2* src = (t & 1) ? B : A;
        float2* dst       = (t & 1) ? A : B;
        fft_stage16<<<dim3(L / 16 / 256, 2), 256, 0, stream>>>(src, dst, 4 * t);
    }
    // result in B
    max_kernel<<<dim3(256, 4), 256, 0, stream>>>(B, partials, N, V);
    reduce_kernel<<<1, 256, 0, stream>>>(partials, cell, 1024);
    slice_norm_kernel<<<dim3((V + 255) / 256, 4), 256, 0, stream>>>(B, out, cell, N, V);
}

// Round 3
// 157.331 us; speedup vs baseline: 2.3694x; 1.2937x over previous
//
#include <hip/hip_runtime.h>

// Reverb via FFT overlap-save cross-correlation. R3: 3-pass FFT.
// L = 2^20 = 256*256*16. Radix-256 Stockham passes (16-thread groups,
// dft16-in-registers + one padded LDS transpose + dft16), then a radix-16
// final pass. Fusions: pack->fwd1, spectral->inv1, slice+max->inv3 (writes
// d_out directly + per-block max partials; no atomics per R1 post-mortem).

#define L_FFT (1 << 20)   // 1,048,576

__device__ __forceinline__ float2 cmul(float2 a, float2 b) {
    return make_float2(a.x * b.x - a.y * b.y, a.x * b.y + a.y * b.x);
}

// radix-4 DFT: o_r = a + b*(-i)^r + c*(-1)^r + d*(i)^r
__device__ __forceinline__ void rad4(float2 a, float2 b, float2 c, float2 d,
                                     float2& o0, float2& o1, float2& o2, float2& o3) {
    float2 apc = make_float2(a.x + c.x, a.y + c.y);
    float2 amc = make_float2(a.x - c.x, a.y - c.y);
    float2 bpd = make_float2(b.x + d.x, b.y + d.y);
    float2 bmd = make_float2(b.x - d.x, b.y - d.y);
    o0 = make_float2(apc.x + bpd.x, apc.y + bpd.y);
    o2 = make_float2(apc.x - bpd.x, apc.y - bpd.y);
    o1 = make_float2(amc.x + bmd.y, amc.y - bmd.x);
    o3 = make_float2(amc.x - bmd.y, amc.y + bmd.x);
}

// 16-pt DFT, natural order in and out (verified in R2 bench).
__device__ __forceinline__ void dft16(float2 x[16]) {
    float2 tt[16];
    rad4(x[0], x[4], x[8],  x[12], tt[0],  tt[1],  tt[2],  tt[3]);
    rad4(x[1], x[5], x[9],  x[13], tt[4],  tt[5],  tt[6],  tt[7]);
    rad4(x[2], x[6], x[10], x[14], tt[8],  tt[9],  tt[10], tt[11]);
    rad4(x[3], x[7], x[11], x[15], tt[12], tt[13], tt[14], tt[15]);
    const float C1 = 0.92387953251128675613f, S1 = 0.38268343236508977173f;
    const float C2 = 0.70710678118654752440f;
    const float2 W1 = make_float2( C1, -S1);
    const float2 W2 = make_float2( C2, -C2);
    const float2 W3 = make_float2( S1, -C1);
    const float2 W6 = make_float2(-C2, -C2);
    const float2 W9 = make_float2(-C1,  S1);
    tt[5]  = cmul(tt[5],  W1);
    tt[6]  = cmul(tt[6],  W2);
    tt[7]  = cmul(tt[7],  W3);
    tt[9]  = cmul(tt[9],  W2);
    tt[10] = make_float2(tt[10].y, -tt[10].x);
    tt[11] = cmul(tt[11], W6);
    tt[13] = cmul(tt[13], W3);
    tt[14] = cmul(tt[14], W6);
    tt[15] = cmul(tt[15], W9);
    rad4(tt[0], tt[4], tt[8],  tt[12], x[0], x[4], x[8],  x[12]);
    rad4(tt[1], tt[5], tt[9],  tt[13], x[1], x[5], x[9],  x[13]);
    rad4(tt[2], tt[6], tt[10], tt[14], x[2], x[6], x[10], x[14]);
    rad4(tt[3], tt[7], tt[11], tt[15], x[3], x[7], x[11], x[15]);
}

// 256-pt FFT across a 16-thread group (thread = q1-lane i, group gi).
// Entry: x[q2] = in[i + 16*q2]. Exit: x[k2] = X[i + 16*k2].
__device__ __forceinline__ void fft256_core(float2 x[16], int i, int gi,
                                            float2 lds[16][16][17]) {
    dft16(x);                           // over q2 -> T[i][k1]
    // internal twiddle w256^{i*k1}
    float sa, ca;
    __sincosf(-6.28318530717958647692f * (float)i * (1.0f / 256.0f), &sa, &ca);
    float2 w1 = make_float2(ca, sa);
    float2 w = w1;
#pragma unroll
    for (int k1 = 1; k1 < 16; ++k1) {
        x[k1] = cmul(x[k1], w);
        w = cmul(w, w1);
    }
#pragma unroll
    for (int k1 = 0; k1 < 16; ++k1) lds[gi][i][k1] = x[k1];
    __syncthreads();
#pragma unroll
    for (int q1 = 0; q1 < 16; ++q1) x[q1] = lds[gi][q1][i];
    dft16(x);                           // over q1 -> X[i + 16*k2]
}

// Stage epilogue: twiddle w_Ln^{np*r} (r = i + 16*k2) and Stockham scatter.
__device__ __forceinline__ void stage256_store(float2 x[16], float2* db,
                                               int g, int i, int J, int log2J,
                                               float invLn) {
    int j = g & (J - 1);
    int np = g >> log2J;
    float base = -6.28318530717958647692f * (float)np * invLn;
    float sa, ca;
    __sincosf(base * (float)i, &sa, &ca);
    float2 w = make_float2(ca, sa);
    __sincosf(base * 16.0f, &sa, &ca);
    float2 w16 = make_float2(ca, sa);
    size_t ob = (size_t)256 * (g - j) + j;
#pragma unroll
    for (int k2 = 0; k2 < 16; ++k2) {
        db[ob + (size_t)(i + 16 * k2) * J] = cmul(x[k2], w);
        w = cmul(w, w16);
    }
}

// Forward pass 1 (J=1) with pack fused: slot0 = seg0+i*seg1,
// slot1 = seg2+i*seg3, slot2 = ir.
__global__ void fwd1_pack(const float* __restrict__ audio,
                          const float* __restrict__ ir,
                          float2* __restrict__ dst, int N, int M, int V) {
    __shared__ float2 lds[16][16][17];
    int tid = threadIdx.x;
    int gi = tid & 15, i = tid >> 4;
    int g = blockIdx.x * 16 + gi;
    int slot = blockIdx.y;
    float2* db = dst + (size_t)slot * L_FFT;

    float2 x[16];
#pragma unroll
    for (int q2 = 0; q2 < 16; ++q2) {
        int idx = g + (i + 16 * q2) * (L_FFT / 256);
        float2 v;
        if (slot == 0) {
            v = make_float2(audio[idx], audio[idx + V]);      // idx+V < N always
        } else if (slot == 1) {
            float a2 = (idx + 2 * V < N) ? audio[idx + 2 * V] : 0.f;
            float a3 = (idx + 3 * V < N) ? audio[idx + 3 * V] : 0.f;
            v = make_float2(a2, a3);
        } else {
            v = make_float2((idx < M) ? ir[idx] : 0.f, 0.f);
        }
        x[q2] = v;
    }
    fft256_core(x, i, gi, lds);
    stage256_store(x, db, g, i, 1, 0, 1.0f / (float)L_FFT);
}

// Generic radix-256 pass (fwd2 / inv2), batch via blockIdx.y.
__global__ void stage256(const float2* __restrict__ src, float2* __restrict__ dst,
                         int J, int log2J, float invLn) {
    __shared__ float2 lds[16][16][17];
    int tid = threadIdx.x;
    int gi = tid & 15, i = tid >> 4;
    int g = blockIdx.x * 16 + gi;
    size_t boff = (size_t)blockIdx.y * L_FFT;
    const float2* sb = src + boff;
    float2* db = dst + boff;

    float2 x[16];
#pragma unroll
    for (int q2 = 0; q2 < 16; ++q2)
        x[q2] = sb[g + (i + 16 * q2) * (L_FFT / 256)];
    fft256_core(x, i, gi, lds);
    stage256_store(x, db, g, i, J, log2J, invLn);
}

// Inverse pass 1 (J=1) with spectral multiply fused: un-pack conj-symmetric
// halves, multiply by conj(H), repack, conj (so forward machinery computes
// the inverse).
__global__ void inv1_spectral(const float2* __restrict__ B,
                              float2* __restrict__ dst) {
    __shared__ float2 lds[16][16][17];
    int tid = threadIdx.x;
    int gi = tid & 15, i = tid >> 4;
    int g = blockIdx.x * 16 + gi;
    int p = blockIdx.y;
    float2* db = dst + (size_t)p * L_FFT;

    float2 x[16];
#pragma unroll
    for (int q2 = 0; q2 < 16; ++q2) {
        int idx = g + (i + 16 * q2) * (L_FFT / 256);
        int kr = (L_FFT - idx) & (L_FFT - 1);
        float2 Z  = B[(size_t)p * L_FFT + idx];
        float2 Zr = B[(size_t)p * L_FFT + kr];
        float2 H  = B[(size_t)2 * L_FFT + idx];
        float2 X0 = make_float2(0.5f * (Z.x + Zr.x), 0.5f * (Z.y - Zr.y));
        float2 X1 = make_float2(0.5f * (Z.y + Zr.y), 0.5f * (Zr.x - Z.x));
        float2 G0 = make_float2(X0.x * H.x + X0.y * H.y, X0.y * H.x - X0.x * H.y);
        float2 G1 = make_float2(X1.x * H.x + X1.y * H.y, X1.y * H.x - X1.x * H.y);
        x[q2] = make_float2(G0.x - G1.y, -(G0.y + G1.x));   // conj(P)
    }
    fft256_core(x, i, gi, lds);
    stage256_store(x, db, g, i, 1, 0, 1.0f / (float)L_FFT);
}

// Forward pass 3: plain radix-16, J = 65536 (np = 0 -> trivial twiddles).
__global__ void fft_stage16(const float2* __restrict__ src,
                            float2* __restrict__ dst) {
    int g = blockIdx.x * blockDim.x + threadIdx.x;   // [0, L/16)
    size_t boff = (size_t)blockIdx.y * L_FFT;
    const float2* sb = src + boff;
    float2* db = dst + boff;
    float2 x[16];
#pragma unroll
    for (int q = 0; q < 16; ++q) x[q] = sb[g + q * (L_FFT / 16)];
    dft16(x);
#pragma unroll
    for (int r = 0; r < 16; ++r) db[g + (size_t)r * (L_FFT / 16)] = x[r];
}

// Inverse pass 3: radix-16 final stage fused with valid-region slice to
// d_out (segment layout) and per-block max partials. w = conj(q)/L; the /L
// cancels under normalization, the conj sign does not.
__global__ void inv3_out(const float2* __restrict__ src, float* __restrict__ out,
                         float* __restrict__ partials, int N, int V) {
    int g = blockIdx.x * blockDim.x + threadIdx.x;   // [0, 65536)
    int p = blockIdx.y;
    const float2* sb = src + (size_t)p * L_FFT;
    float2 x[16];
#pragma unroll
    for (int q = 0; q < 16; ++q) x[q] = sb[g + q * (L_FFT / 16)];
    dft16(x);
    int se = 2 * p, so = 2 * p + 1;
    int lenO = (so == 3) ? (N - 3 * V) : V;
    float m = 0.f;
#pragma unroll
    for (int r = 0; r < 16; ++r) {
        int n = g + r * (L_FFT / 16);
        float vr = x[r].x, vi = -x[r].y;
        if (n < V)    { out[(size_t)se * V + n] = vr; m = fmaxf(m, fabsf(vr)); }
        if (n < lenO) { out[(size_t)so * V + n] = vi; m = fmaxf(m, fabsf(vi)); }
    }
    for (int o = 32; o > 0; o >>= 1) m = fmaxf(m, __shfl_xor(m, o));
    __shared__ float sm[4];
    int lane = threadIdx.x & 63, wv = threadIdx.x >> 6;
    if (lane == 0) sm[wv] = m;
    __syncthreads();
    if (threadIdx.x == 0)
        partials[blockIdx.y * gridDim.x + blockIdx.x] =
            fmaxf(fmaxf(sm[0], sm[1]), fmaxf(sm[2], sm[3]));
}

__global__ void reduce_kernel(const float* __restrict__ partials,
                              float* __restrict__ cell, int np) {
    float m = 0.f;
    for (int i = threadIdx.x; i < np; i += blockDim.x) m = fmaxf(m, partials[i]);
    for (int o = 32; o > 0; o >>= 1) m = fmaxf(m, __shfl_xor(m, o));
    __shared__ float sm[4];
    int lane = threadIdx.x & 63, wv = threadIdx.x >> 6;
    if (lane == 0) sm[wv] = m;
    __syncthreads();
    if (threadIdx.x == 0)
        cell[0] = fmaxf(fmaxf(sm[0], sm[1]), fmaxf(sm[2], sm[3]));
}

__global__ void normalize_kernel(float* __restrict__ out,
                                 const float* __restrict__ cell, int N) {
    int t = blockIdx.x * blockDim.x + threadIdx.x;
    if (t >= N) return;
    out[t] = out[t] / cell[0];
}

extern "C" void kernel_launch(void* const* d_in, const int* in_sizes, int n_in,
                              void* d_out, int out_size, void* d_ws, size_t ws_size,
                              hipStream_t stream) {
    const int L = L_FFT;
    const float* audio = (const float*)d_in[0];
    const float* ir    = (const float*)d_in[1];
    float* out = (float*)d_out;

    const int N = in_sizes[0];          // 2,646,000
    const int M = in_sizes[1];          // 220,500
    const int V = L - M + 1;            // 828,077

    float2* A = (float2*)d_ws;
    float2* B = A + (size_t)3 * L;
    float* partials = (float*)(B + (size_t)3 * L);
    float* cell = partials + 512;

    const float invLn2 = 1.0f / 4096.0f;   // pass-2 Ln = L/256

    // forward: audio -> B -> A -> B   (batch 3: seg01, seg23, ir)
    fwd1_pack<<<dim3(256, 3), 256, 0, stream>>>(audio, ir, B, N, M, V);
    stage256<<<dim3(256, 3), 256, 0, stream>>>(B, A, 256, 8, invLn2);
    fft_stage16<<<dim3(256, 3), 256, 0, stream>>>(A, B);
    // inverse: B -> A -> B -> out    (batch 2)
    inv1_spectral<<<dim3(256, 2), 256, 0, stream>>>(B, A);
    stage256<<<dim3(256, 2), 256, 0, stream>>>(A, B, 256, 8, invLn2);
    inv3_out<<<dim3(256, 2), 256, 0, stream>>>(B, out, partials, N, V);
    // normalize
    reduce_kernel<<<1, 256, 0, stream>>>(partials, cell, 512);
    normalize_kernel<<<(N + 255) / 256, 256, 0, stream>>>(out, cell, N);
}

// Round 4
// 152.730 us; speedup vs baseline: 2.4408x; 1.0301x over previous
//
#include <hip/hip_runtime.h>

// Reverb via FFT overlap-save cross-correlation. R4.
// L = 2^20 = 256*256*16; 3-pass radix-256/256/16 Stockham.
// R4 fusion: forward pass 3 + spectral multiply in ONE kernel
// (fwd3_spectral) — bin k=g+r*65536 mirrors to group 65536-g, so a block
// holding the (g, 65536-g) pair completes the fwd dft16, exchanges X via
// LDS, multiplies by conj(H) (H needs no mirror), and writes conj(P)
// directly: saves the 25 MB X round-trip + 17 MB mirror re-read vs R3.
// Inverse = two plain radix-256 passes + fused slice/max final pass.
// normalize re-reduces the 512 partials per block (no atomics, R1 lesson).

#define L_FFT (1 << 20)   // 1,048,576

__device__ __forceinline__ float2 cmul(float2 a, float2 b) {
    return make_float2(a.x * b.x - a.y * b.y, a.x * b.y + a.y * b.x);
}

// radix-4 DFT: o_r = a + b*(-i)^r + c*(-1)^r + d*(i)^r
__device__ __forceinline__ void rad4(float2 a, float2 b, float2 c, float2 d,
                                     float2& o0, float2& o1, float2& o2, float2& o3) {
    float2 apc = make_float2(a.x + c.x, a.y + c.y);
    float2 amc = make_float2(a.x - c.x, a.y - c.y);
    float2 bpd = make_float2(b.x + d.x, b.y + d.y);
    float2 bmd = make_float2(b.x - d.x, b.y - d.y);
    o0 = make_float2(apc.x + bpd.x, apc.y + bpd.y);
    o2 = make_float2(apc.x - bpd.x, apc.y - bpd.y);
    o1 = make_float2(amc.x + bmd.y, amc.y - bmd.x);
    o3 = make_float2(amc.x - bmd.y, amc.y + bmd.x);
}

// 16-pt DFT, natural order in and out (bench-verified R2/R3).
__device__ __forceinline__ void dft16(float2 x[16]) {
    float2 tt[16];
    rad4(x[0], x[4], x[8],  x[12], tt[0],  tt[1],  tt[2],  tt[3]);
    rad4(x[1], x[5], x[9],  x[13], tt[4],  tt[5],  tt[6],  tt[7]);
    rad4(x[2], x[6], x[10], x[14], tt[8],  tt[9],  tt[10], tt[11]);
    rad4(x[3], x[7], x[11], x[15], tt[12], tt[13], tt[14], tt[15]);
    const float C1 = 0.92387953251128675613f, S1 = 0.38268343236508977173f;
    const float C2 = 0.70710678118654752440f;
    const float2 W1 = make_float2( C1, -S1);
    const float2 W2 = make_float2( C2, -C2);
    const float2 W3 = make_float2( S1, -C1);
    const float2 W6 = make_float2(-C2, -C2);
    const float2 W9 = make_float2(-C1,  S1);
    tt[5]  = cmul(tt[5],  W1);
    tt[6]  = cmul(tt[6],  W2);
    tt[7]  = cmul(tt[7],  W3);
    tt[9]  = cmul(tt[9],  W2);
    tt[10] = make_float2(tt[10].y, -tt[10].x);
    tt[11] = cmul(tt[11], W6);
    tt[13] = cmul(tt[13], W3);
    tt[14] = cmul(tt[14], W6);
    tt[15] = cmul(tt[15], W9);
    rad4(tt[0], tt[4], tt[8],  tt[12], x[0], x[4], x[8],  x[12]);
    rad4(tt[1], tt[5], tt[9],  tt[13], x[1], x[5], x[9],  x[13]);
    rad4(tt[2], tt[6], tt[10], tt[14], x[2], x[6], x[10], x[14]);
    rad4(tt[3], tt[7], tt[11], tt[15], x[3], x[7], x[11], x[15]);
}

// 256-pt FFT across a 16-thread group (thread = q1-lane i, group gi).
__device__ __forceinline__ void fft256_core(float2 x[16], int i, int gi,
                                            float2 lds[16][16][17]) {
    dft16(x);
    float sa, ca;
    __sincosf(-6.28318530717958647692f * (float)i * (1.0f / 256.0f), &sa, &ca);
    float2 w1 = make_float2(ca, sa);
    float2 w = w1;
#pragma unroll
    for (int k1 = 1; k1 < 16; ++k1) {
        x[k1] = cmul(x[k1], w);
        w = cmul(w, w1);
    }
#pragma unroll
    for (int k1 = 0; k1 < 16; ++k1) lds[gi][i][k1] = x[k1];
    __syncthreads();
#pragma unroll
    for (int q1 = 0; q1 < 16; ++q1) x[q1] = lds[gi][q1][i];
    dft16(x);
}

// Stage twiddle w_Ln^{np*r} (r = i + 16*k2) + Stockham scatter.
__device__ __forceinline__ void stage256_store(float2 x[16], float2* db,
                                               int g, int i, int J, int log2J,
                                               float invLn) {
    int j = g & (J - 1);
    int np = g >> log2J;
    float base = -6.28318530717958647692f * (float)np * invLn;
    float sa, ca;
    __sincosf(base * (float)i, &sa, &ca);
    float2 w = make_float2(ca, sa);
    __sincosf(base * 16.0f, &sa, &ca);
    float2 w16 = make_float2(ca, sa);
    size_t ob = (size_t)256 * (g - j) + j;
#pragma unroll
    for (int k2 = 0; k2 < 16; ++k2) {
        db[ob + (size_t)(i + 16 * k2) * J] = cmul(x[k2], w);
        w = cmul(w, w16);
    }
}

// Forward pass 1 (J=1) with pack fused.
__global__ void fwd1_pack(const float* __restrict__ audio,
                          const float* __restrict__ ir,
                          float2* __restrict__ dst, int N, int M, int V) {
    __shared__ float2 lds[16][16][17];
    int tid = threadIdx.x;
    int gi = tid & 15, i = tid >> 4;
    int g = blockIdx.x * 16 + gi;
    int slot = blockIdx.y;
    float2* db = dst + (size_t)slot * L_FFT;

    float2 x[16];
#pragma unroll
    for (int q2 = 0; q2 < 16; ++q2) {
        int idx = g + (i + 16 * q2) * (L_FFT / 256);
        float2 v;
        if (slot == 0) {
            v = make_float2(audio[idx], audio[idx + V]);
        } else if (slot == 1) {
            float a2 = (idx + 2 * V < N) ? audio[idx + 2 * V] : 0.f;
            float a3 = (idx + 3 * V < N) ? audio[idx + 3 * V] : 0.f;
            v = make_float2(a2, a3);
        } else {
            v = make_float2((idx < M) ? ir[idx] : 0.f, 0.f);
        }
        x[q2] = v;
    }
    fft256_core(x, i, gi, lds);
    stage256_store(x, db, g, i, 1, 0, 1.0f / (float)L_FFT);
}

// Generic radix-256 pass, batch via blockIdx.y.
__global__ void stage256(const float2* __restrict__ src, float2* __restrict__ dst,
                         int J, int log2J, float invLn) {
    __shared__ float2 lds[16][16][17];
    int tid = threadIdx.x;
    int gi = tid & 15, i = tid >> 4;
    int g = blockIdx.x * 16 + gi;
    size_t boff = (size_t)blockIdx.y * L_FFT;
    const float2* sb = src + boff;
    float2* db = dst + boff;

    float2 x[16];
#pragma unroll
    for (int q2 = 0; q2 < 16; ++q2)
        x[q2] = sb[g + (i + 16 * q2) * (L_FFT / 256)];
    fft256_core(x, i, gi, lds);
    stage256_store(x, db, g, i, J, log2J, invLn);
}

// Fused: forward pass 3 (radix-16 final, trivial twiddles) + spectral
// multiply. Lanes 0..127 handle g = blk*128+j; lanes 128..255 handle the
// mirror group (65536-g)&65535. X exchanged via LDS; H is bin-local.
// Writes conj(P) into dst slots 0,1 (natural k order, coalesced).
__global__ void fwd3_spectral(const float2* __restrict__ A,
                              float2* __restrict__ B) {
    __shared__ float2 XS[256][17];   // +1 pad: 2-way max bank aliasing
    int tid = threadIdx.x;
    int isFwd = (tid < 128);
    int j = isFwd ? tid : (tid - 128);
    int gf = blockIdx.x * 128 + j;               // fwd lane group
    int g = isFwd ? gf : ((65536 - gf) & 65535); // own group
    int ptid = isFwd ? (tid + 128) : (tid - 128);

    // H for own bins: dft16 of IR slot (slot 2), k = g + r*65536
    float2 h[16];
#pragma unroll
    for (int q = 0; q < 16; ++q)
        h[q] = A[(size_t)2 * L_FFT + g + (size_t)q * 65536];
    dft16(h);

#pragma unroll
    for (int p = 0; p < 2; ++p) {
        float2 x[16];
#pragma unroll
        for (int q = 0; q < 16; ++q)
            x[q] = A[(size_t)p * L_FFT + g + (size_t)q * 65536];
        dft16(x);                                 // Z[r] = X[g + r*65536]
        __syncthreads();                          // guard LDS reuse (p loop)
#pragma unroll
        for (int r = 0; r < 16; ++r) XS[tid][r] = x[r];
        __syncthreads();
#pragma unroll
        for (int r = 0; r < 16; ++r) {
            int mi = (g == 0) ? ((16 - r) & 15) : (15 - r);
            float2 Z  = x[r];
            float2 Zr = XS[ptid][mi];             // Z[L-k]
            float2 H  = h[r];
            float2 X0 = make_float2(0.5f * (Z.x + Zr.x), 0.5f * (Z.y - Zr.y));
            float2 X1 = make_float2(0.5f * (Z.y + Zr.y), 0.5f * (Zr.x - Z.x));
            float2 G0 = make_float2(X0.x * H.x + X0.y * H.y, X0.y * H.x - X0.x * H.y);
            float2 G1 = make_float2(X1.x * H.x + X1.y * H.y, X1.y * H.x - X1.x * H.y);
            // P = G0 + i*G1, store conj(P)
            B[(size_t)p * L_FFT + g + (size_t)r * 65536] =
                make_float2(G0.x - G1.y, -(G0.y + G1.x));
        }
    }
}

// Inverse pass 3: radix-16 final stage fused with valid-region slice to
// d_out and per-block max partials. w = conj(q)/L; /L cancels under
// normalization, the conj sign does not.
__global__ void inv3_out(const float2* __restrict__ src, float* __restrict__ out,
                         float* __restrict__ partials, int N, int V) {
    int g = blockIdx.x * blockDim.x + threadIdx.x;   // [0, 65536)
    int p = blockIdx.y;
    const float2* sb = src + (size_t)p * L_FFT;
    float2 x[16];
#pragma unroll
    for (int q = 0; q < 16; ++q) x[q] = sb[g + q * (L_FFT / 16)];
    dft16(x);
    int se = 2 * p, so = 2 * p + 1;
    int lenO = (so == 3) ? (N - 3 * V) : V;
    float m = 0.f;
#pragma unroll
    for (int r = 0; r < 16; ++r) {
        int n = g + r * (L_FFT / 16);
        float vr = x[r].x, vi = -x[r].y;
        if (n < V)    { out[(size_t)se * V + n] = vr; m = fmaxf(m, fabsf(vr)); }
        if (n < lenO) { out[(size_t)so * V + n] = vi; m = fmaxf(m, fabsf(vi)); }
    }
    for (int o = 32; o > 0; o >>= 1) m = fmaxf(m, __shfl_xor(m, o));
    __shared__ float sm[4];
    int lane = threadIdx.x & 63, wv = threadIdx.x >> 6;
    if (lane == 0) sm[wv] = m;
    __syncthreads();
    if (threadIdx.x == 0)
        partials[blockIdx.y * gridDim.x + blockIdx.x] =
            fmaxf(fmaxf(sm[0], sm[1]), fmaxf(sm[2], sm[3]));
}

// Fused reduce + normalize: each block reduces the 512 partials (L2-hot)
// then grid-strides over out.
__global__ void norm_fused(float* __restrict__ out,
                           const float* __restrict__ partials, int N) {
    float m = 0.f;
    for (int i = threadIdx.x; i < 512; i += 256) m = fmaxf(m, partials[i]);
    for (int o = 32; o > 0; o >>= 1) m = fmaxf(m, __shfl_xor(m, o));
    __shared__ float sm[4];
    int lane = threadIdx.x & 63, wv = threadIdx.x >> 6;
    if (lane == 0) sm[wv] = m;
    __syncthreads();
    float mx = fmaxf(fmaxf(sm[0], sm[1]), fmaxf(sm[2], sm[3]));
    float inv = 1.0f / mx;
    int stride = gridDim.x * blockDim.x;
    for (int t = blockIdx.x * blockDim.x + threadIdx.x; t < N; t += stride)
        out[t] *= inv;
}

extern "C" void kernel_launch(void* const* d_in, const int* in_sizes, int n_in,
                              void* d_out, int out_size, void* d_ws, size_t ws_size,
                              hipStream_t stream) {
    const int L = L_FFT;
    const float* audio = (const float*)d_in[0];
    const float* ir    = (const float*)d_in[1];
    float* out = (float*)d_out;

    const int N = in_sizes[0];          // 2,646,000
    const int M = in_sizes[1];          // 220,500
    const int V = L - M + 1;            // 828,077

    float2* A = (float2*)d_ws;
    float2* B = A + (size_t)3 * L;
    float* partials = (float*)(B + (size_t)3 * L);

    const float invL   = 1.0f / (float)L;
    const float invLn2 = 1.0f / 4096.0f;   // pass-2 Ln = L/256

    // forward: audio/ir -> B -> A, then fused pass3+spectral: A -> B(P)
    fwd1_pack<<<dim3(256, 3), 256, 0, stream>>>(audio, ir, B, N, M, V);
    stage256<<<dim3(256, 3), 256, 0, stream>>>(B, A, 256, 8, invLn2);
    fwd3_spectral<<<257, 256, 0, stream>>>(A, B);
    // inverse (forward machinery on conj(P)): B -> A -> B -> out
    stage256<<<dim3(256, 2), 256, 0, stream>>>(B, A, 1, 0, invL);
    stage256<<<dim3(256, 2), 256, 0, stream>>>(A, B, 256, 8, invLn2);
    inv3_out<<<dim3(256, 2), 256, 0, stream>>>(B, out, partials, N, V);
    norm_fused<<<1024, 256, 0, stream>>>(out, partials, N);
}

// Round 5
// 133.529 us; speedup vs baseline: 2.7918x; 1.1438x over previous
//
#include <hip/hip_runtime.h>

// Reverb via FFT overlap-save cross-correlation. R5.
// L = 2^20 = 256*256*16; 3-pass radix-256/256/16 Stockham.
// R5 fix: fft256_core's LDS transpose had group stride 272 === 0 (mod 16
// float2 bank-pairs) -> the lane-varying index (gi) vanished from the bank
// computation -> 16-way conflicts on BOTH phases (5.7x LDS cost, m136).
// New layout: flat array, group stride 273 (===1 mod 16), row stride 17
// (===1 mod 16): bank-pair = (gi + row + col) mod 16 -> 4 lanes/bank =
// the b64 wave64 conflict-free floor. Math unchanged.

#define L_FFT (1 << 20)   // 1,048,576
#define GSTRIDE 273       // LDS group stride (float2): 273 % 16 == 1

__device__ __forceinline__ float2 cmul(float2 a, float2 b) {
    return make_float2(a.x * b.x - a.y * b.y, a.x * b.y + a.y * b.x);
}

// radix-4 DFT: o_r = a + b*(-i)^r + c*(-1)^r + d*(i)^r
__device__ __forceinline__ void rad4(float2 a, float2 b, float2 c, float2 d,
                                     float2& o0, float2& o1, float2& o2, float2& o3) {
    float2 apc = make_float2(a.x + c.x, a.y + c.y);
    float2 amc = make_float2(a.x - c.x, a.y - c.y);
    float2 bpd = make_float2(b.x + d.x, b.y + d.y);
    float2 bmd = make_float2(b.x - d.x, b.y - d.y);
    o0 = make_float2(apc.x + bpd.x, apc.y + bpd.y);
    o2 = make_float2(apc.x - bpd.x, apc.y - bpd.y);
    o1 = make_float2(amc.x + bmd.y, amc.y - bmd.x);
    o3 = make_float2(amc.x - bmd.y, amc.y + bmd.x);
}

// 16-pt DFT, natural order in and out (bench-verified R2-R4).
__device__ __forceinline__ void dft16(float2 x[16]) {
    float2 tt[16];
    rad4(x[0], x[4], x[8],  x[12], tt[0],  tt[1],  tt[2],  tt[3]);
    rad4(x[1], x[5], x[9],  x[13], tt[4],  tt[5],  tt[6],  tt[7]);
    rad4(x[2], x[6], x[10], x[14], tt[8],  tt[9],  tt[10], tt[11]);
    rad4(x[3], x[7], x[11], x[15], tt[12], tt[13], tt[14], tt[15]);
    const float C1 = 0.92387953251128675613f, S1 = 0.38268343236508977173f;
    const float C2 = 0.70710678118654752440f;
    const float2 W1 = make_float2( C1, -S1);
    const float2 W2 = make_float2( C2, -C2);
    const float2 W3 = make_float2( S1, -C1);
    const float2 W6 = make_float2(-C2, -C2);
    const float2 W9 = make_float2(-C1,  S1);
    tt[5]  = cmul(tt[5],  W1);
    tt[6]  = cmul(tt[6],  W2);
    tt[7]  = cmul(tt[7],  W3);
    tt[9]  = cmul(tt[9],  W2);
    tt[10] = make_float2(tt[10].y, -tt[10].x);
    tt[11] = cmul(tt[11], W6);
    tt[13] = cmul(tt[13], W3);
    tt[14] = cmul(tt[14], W6);
    tt[15] = cmul(tt[15], W9);
    rad4(tt[0], tt[4], tt[8],  tt[12], x[0], x[4], x[8],  x[12]);
    rad4(tt[1], tt[5], tt[9],  tt[13], x[1], x[5], x[9],  x[13]);
    rad4(tt[2], tt[6], tt[10], tt[14], x[2], x[6], x[10], x[14]);
    rad4(tt[3], tt[7], tt[11], tt[15], x[3], x[7], x[11], x[15]);
}

// 256-pt FFT across a 16-thread group (thread = q1-lane i, group gi).
// LDS layout: lds[gi*GSTRIDE + row*17 + col] — both strides === 1 (mod 16)
// so bank-pair = (gi + row + col) mod 16: 4-way = b64 conflict-free floor.
__device__ __forceinline__ void fft256_core(float2 x[16], int i, int gi,
                                            float2* lds) {
    dft16(x);
    float sa, ca;
    __sincosf(-6.28318530717958647692f * (float)i * (1.0f / 256.0f), &sa, &ca);
    float2 w1 = make_float2(ca, sa);
    float2 w = w1;
#pragma unroll
    for (int k1 = 1; k1 < 16; ++k1) {
        x[k1] = cmul(x[k1], w);
        w = cmul(w, w1);
    }
    float2* base = lds + gi * GSTRIDE;
#pragma unroll
    for (int k1 = 0; k1 < 16; ++k1) base[i * 17 + k1] = x[k1];
    __syncthreads();
#pragma unroll
    for (int q1 = 0; q1 < 16; ++q1) x[q1] = base[q1 * 17 + i];
    dft16(x);
}

// Stage twiddle w_Ln^{np*r} (r = i + 16*k2) + Stockham scatter.
__device__ __forceinline__ void stage256_store(float2 x[16], float2* db,
                                               int g, int i, int J, int log2J,
                                               float invLn) {
    int j = g & (J - 1);
    int np = g >> log2J;
    float base = -6.28318530717958647692f * (float)np * invLn;
    float sa, ca;
    __sincosf(base * (float)i, &sa, &ca);
    float2 w = make_float2(ca, sa);
    __sincosf(base * 16.0f, &sa, &ca);
    float2 w16 = make_float2(ca, sa);
    size_t ob = (size_t)256 * (g - j) + j;
#pragma unroll
    for (int k2 = 0; k2 < 16; ++k2) {
        db[ob + (size_t)(i + 16 * k2) * J] = cmul(x[k2], w);
        w = cmul(w, w16);
    }
}

// Forward pass 1 (J=1) with pack fused.
__global__ void fwd1_pack(const float* __restrict__ audio,
                          const float* __restrict__ ir,
                          float2* __restrict__ dst, int N, int M, int V) {
    __shared__ float2 lds[16 * GSTRIDE];
    int tid = threadIdx.x;
    int gi = tid & 15, i = tid >> 4;
    int g = blockIdx.x * 16 + gi;
    int slot = blockIdx.y;
    float2* db = dst + (size_t)slot * L_FFT;

    float2 x[16];
#pragma unroll
    for (int q2 = 0; q2 < 16; ++q2) {
        int idx = g + (i + 16 * q2) * (L_FFT / 256);
        float2 v;
        if (slot == 0) {
            v = make_float2(audio[idx], audio[idx + V]);
        } else if (slot == 1) {
            float a2 = (idx + 2 * V < N) ? audio[idx + 2 * V] : 0.f;
            float a3 = (idx + 3 * V < N) ? audio[idx + 3 * V] : 0.f;
            v = make_float2(a2, a3);
        } else {
            v = make_float2((idx < M) ? ir[idx] : 0.f, 0.f);
        }
        x[q2] = v;
    }
    fft256_core(x, i, gi, lds);
    stage256_store(x, db, g, i, 1, 0, 1.0f / (float)L_FFT);
}

// Generic radix-256 pass, batch via blockIdx.y.
__global__ void stage256(const float2* __restrict__ src, float2* __restrict__ dst,
                         int J, int log2J, float invLn) {
    __shared__ float2 lds[16 * GSTRIDE];
    int tid = threadIdx.x;
    int gi = tid & 15, i = tid >> 4;
    int g = blockIdx.x * 16 + gi;
    size_t boff = (size_t)blockIdx.y * L_FFT;
    const float2* sb = src + boff;
    float2* db = dst + boff;

    float2 x[16];
#pragma unroll
    for (int q2 = 0; q2 < 16; ++q2)
        x[q2] = sb[g + (i + 16 * q2) * (L_FFT / 256)];
    fft256_core(x, i, gi, lds);
    stage256_store(x, db, g, i, J, log2J, invLn);
}

// Fused: forward pass 3 (radix-16 final, trivial twiddles) + spectral
// multiply. Lanes 0..127: g = blk*128+j; lanes 128..255: mirror group
// (65536-g)&65535. X exchanged via LDS (tid*17 stride: conflict-free);
// H is bin-local. Writes conj(P) into dst slots 0,1.
__global__ void fwd3_spectral(const float2* __restrict__ A,
                              float2* __restrict__ B) {
    __shared__ float2 XS[256 * 17];
    int tid = threadIdx.x;
    int isFwd = (tid < 128);
    int j = isFwd ? tid : (tid - 128);
    int gf = blockIdx.x * 128 + j;
    int g = isFwd ? gf : ((65536 - gf) & 65535);
    int ptid = isFwd ? (tid + 128) : (tid - 128);

    float2 h[16];
#pragma unroll
    for (int q = 0; q < 16; ++q)
        h[q] = A[(size_t)2 * L_FFT + g + (size_t)q * 65536];
    dft16(h);

#pragma unroll
    for (int p = 0; p < 2; ++p) {
        float2 x[16];
#pragma unroll
        for (int q = 0; q < 16; ++q)
            x[q] = A[(size_t)p * L_FFT + g + (size_t)q * 65536];
        dft16(x);
        __syncthreads();
#pragma unroll
        for (int r = 0; r < 16; ++r) XS[tid * 17 + r] = x[r];
        __syncthreads();
#pragma unroll
        for (int r = 0; r < 16; ++r) {
            int mi = (g == 0) ? ((16 - r) & 15) : (15 - r);
            float2 Z  = x[r];
            float2 Zr = XS[ptid * 17 + mi];
            float2 H  = h[r];
            float2 X0 = make_float2(0.5f * (Z.x + Zr.x), 0.5f * (Z.y - Zr.y));
            float2 X1 = make_float2(0.5f * (Z.y + Zr.y), 0.5f * (Zr.x - Z.x));
            float2 G0 = make_float2(X0.x * H.x + X0.y * H.y, X0.y * H.x - X0.x * H.y);
            float2 G1 = make_float2(X1.x * H.x + X1.y * H.y, X1.y * H.x - X1.x * H.y);
            B[(size_t)p * L_FFT + g + (size_t)r * 65536] =
                make_float2(G0.x - G1.y, -(G0.y + G1.x));
        }
    }
}

// Inverse pass 3: radix-16 final stage fused with valid-region slice to
// d_out and per-block max partials.
__global__ void inv3_out(const float2* __restrict__ src, float* __restrict__ out,
                         float* __restrict__ partials, int N, int V) {
    int g = blockIdx.x * blockDim.x + threadIdx.x;   // [0, 65536)
    int p = blockIdx.y;
    const float2* sb = src + (size_t)p * L_FFT;
    float2 x[16];
#pragma unroll
    for (int q = 0; q < 16; ++q) x[q] = sb[g + q * (L_FFT / 16)];
    dft16(x);
    int se = 2 * p, so = 2 * p + 1;
    int lenO = (so == 3) ? (N - 3 * V) : V;
    float m = 0.f;
#pragma unroll
    for (int r = 0; r < 16; ++r) {
        int n = g + r * (L_FFT / 16);
        float vr = x[r].x, vi = -x[r].y;
        if (n < V)    { out[(size_t)se * V + n] = vr; m = fmaxf(m, fabsf(vr)); }
        if (n < lenO) { out[(size_t)so * V + n] = vi; m = fmaxf(m, fabsf(vi)); }
    }
    for (int o = 32; o > 0; o >>= 1) m = fmaxf(m, __shfl_xor(m, o));
    __shared__ float sm[4];
    int lane = threadIdx.x & 63, wv = threadIdx.x >> 6;
    if (lane == 0) sm[wv] = m;
    __syncthreads();
    if (threadIdx.x == 0)
        partials[blockIdx.y * gridDim.x + blockIdx.x] =
            fmaxf(fmaxf(sm[0], sm[1]), fmaxf(sm[2], sm[3]));
}

// Fused reduce + normalize.
__global__ void norm_fused(float* __restrict__ out,
                           const float* __restrict__ partials, int N) {
    float m = 0.f;
    for (int i = threadIdx.x; i < 512; i += 256) m = fmaxf(m, partials[i]);
    for (int o = 32; o > 0; o >>= 1) m = fmaxf(m, __shfl_xor(m, o));
    __shared__ float sm[4];
    int lane = threadIdx.x & 63, wv = threadIdx.x >> 6;
    if (lane == 0) sm[wv] = m;
    __syncthreads();
    float mx = fmaxf(fmaxf(sm[0], sm[1]), fmaxf(sm[2], sm[3]));
    float inv = 1.0f / mx;
    int stride = gridDim.x * blockDim.x;
    for (int t = blockIdx.x * blockDim.x + threadIdx.x; t < N; t += stride)
        out[t] *= inv;
}

extern "C" void kernel_launch(void* const* d_in, const int* in_sizes, int n_in,
                              void* d_out, int out_size, void* d_ws, size_t ws_size,
                              hipStream_t stream) {
    const int L = L_FFT;
    const float* audio = (const float*)d_in[0];
    const float* ir    = (const float*)d_in[1];
    float* out = (float*)d_out;

    const int N = in_sizes[0];          // 2,646,000
    const int M = in_sizes[1];          // 220,500
    const int V = L - M + 1;            // 828,077

    float2* A = (float2*)d_ws;
    float2* B = A + (size_t)3 * L;
    float* partials = (float*)(B + (size_t)3 * L);

    const float invL   = 1.0f / (float)L;
    const float invLn2 = 1.0f / 4096.0f;   // pass-2 Ln = L/256

    // forward: audio/ir -> B -> A, then fused pass3+spectral: A -> B(P)
    fwd1_pack<<<dim3(256, 3), 256, 0, stream>>>(audio, ir, B, N, M, V);
    stage256<<<dim3(256, 3), 256, 0, stream>>>(B, A, 256, 8, invLn2);
    fwd3_spectral<<<257, 256, 0, stream>>>(A, B);
    // inverse (forward machinery on conj(P)): B -> A -> B -> out
    stage256<<<dim3(256, 2), 256, 0, stream>>>(B, A, 1, 0, invL);
    stage256<<<dim3(256, 2), 256, 0, stream>>>(A, B, 256, 8, invLn2);
    inv3_out<<<dim3(256, 2), 256, 0, stream>>>(B, out, partials, N, V);
    norm_fused<<<1024, 256, 0, stream>>>(out, partials, N);
}